// Round 4
// baseline (192.574 us; speedup 1.0000x reference)
//
#include <hip/hip_runtime.h>
#include <hip/hip_bf16.h>

// Shapes fixed by the problem:
// B=4, S=1024, D=512, H=64, DK=8, FF=2048, NQ=8. Mtok = B*S = 4096.

typedef short short8 __attribute__((ext_vector_type(8)));
typedef float floatx4 __attribute__((ext_vector_type(4)));

__device__ __forceinline__ unsigned short f2bf_bits(float f) {
  __hip_bfloat16 h = __float2bfloat16(f);
  return *reinterpret_cast<unsigned short*>(&h);
}

#define GLOBAL_LOAD_LDS16(g, l)                                               \
  __builtin_amdgcn_global_load_lds(                                           \
      (const __attribute__((address_space(1))) void*)(g),                     \
      (__attribute__((address_space(3))) void*)(l), 16, 0, 0)

// Compiler does NOT model global_load_lds's LDS write as aliasing later LDS
// reads (round-3 NaN). Explicit waits, with memory clobber to pin ordering:
#define WAIT_VMCNT0()  asm volatile("s_waitcnt vmcnt(0)" ::: "memory")
#define WAIT_LGKM0()   asm volatile("s_waitcnt lgkmcnt(0)" ::: "memory")

// ---------------------------------------------------------------------------
// Single-wave GEMM: C[M,N] = A[M,K] @ W[N,K]^T + bias[N].
// Block = 64 threads = 1 wave computing a 64x64 tile via 4x4 of 16x16x32
// MFMA, BK=64. No __syncthreads (single wave); correctness relies on the
// explicit waitcnt fences above. Latency hidden by ~10 resident single-wave
// blocks/CU (16 KB LDS each).
// Staging: 16x global_load_lds(16B) with XOR chunk swizzle
//   (phys chunk p of row r holds logical chunk p ^ (r&7)) -> conflict-free
//   ds_read_b128 fragments (2-way max, free per m136).
// modes: 0 = fp32 store (acc+bias)
//        1 = quantum epilogue: LDS-transpose acc, o = cumprod-of-cos with
//            z0 head element, store bf16 to mixout. If *gate != 1, also
//            store plain fp32 (acc+bias) to Cf for the classical path.
//        2 = bf16 store of relu(acc+bias) to Cb.
// blockIdx.z batching (for K/V): z==1 uses Wb/biasb/Cfb.
// Whole grid early-exits when *skipgate == 1.0f.
// ---------------------------------------------------------------------------
__global__ __launch_bounds__(64) void gemm64(
    const __hip_bfloat16* __restrict__ A,
    const __hip_bfloat16* __restrict__ W,
    const __hip_bfloat16* __restrict__ Wb,
    const float* __restrict__ bias,
    const float* __restrict__ biasb,
    float* __restrict__ Cf,
    float* __restrict__ Cfb,
    __hip_bfloat16* __restrict__ Cb,
    int M, int N, int K, int mode,
    const float* __restrict__ theta,
    const float* __restrict__ gate,
    __hip_bfloat16* __restrict__ mixout,
    const float* __restrict__ skipgate)
{
  if (skipgate != nullptr && *skipgate == 1.0f) return;
  if (blockIdx.z == 1) { W = Wb; bias = biasb; Cf = Cfb; }
  __shared__ __align__(16) __hip_bfloat16 sh[8192];   // As=sh[0..4095], Bs=+4096
  __hip_bfloat16* As = sh;
  __hip_bfloat16* Bs = sh + 4096;
  const int lane = threadIdx.x;
  const long m0 = (long)blockIdx.x * 64;
  const long n0 = (long)blockIdx.y * 64;

  floatx4 acc[4][4];
#pragma unroll
  for (int i = 0; i < 4; ++i)
#pragma unroll
    for (int j = 0; j < 4; ++j)
      acc[i][j] = (floatx4){0.f, 0.f, 0.f, 0.f};

  const int srow = lane >> 3;       // 0..7: row within 8-row staging block
  const int schunk = lane & 7;      // physical 16B chunk
  const int gchunk = schunk ^ srow; // logical chunk (row&7 == srow)
  const int frow = lane & 15;
  const int fk = lane >> 4;         // 0..3

  for (int kt = 0; kt < K; kt += 64) {
    // prior iteration's ds_reads fully retired before LDS is overwritten
    WAIT_LGKM0();
#pragma unroll
    for (int ib = 0; ib < 8; ++ib) {
      const int row = ib * 8 + srow;
      GLOBAL_LOAD_LDS16(A + (m0 + row) * K + kt + gchunk * 8, As + ib * 512);
      GLOBAL_LOAD_LDS16(W + (n0 + row) * K + kt + gchunk * 8, Bs + ib * 512);
    }
    // LDS-DMA landed before fragment reads (compiler won't insert this)
    WAIT_VMCNT0();
    short8 af[2][4], bf[2][4];
#pragma unroll
    for (int ks = 0; ks < 2; ++ks)
#pragma unroll
      for (int i = 0; i < 4; ++i) {
        const int ar = i * 16 + frow;
        af[ks][i] = *(const short8*)(As + ar * 64 + (((ks * 4 + fk) ^ (ar & 7)) << 3));
        bf[ks][i] = *(const short8*)(Bs + ar * 64 + (((ks * 4 + fk) ^ (ar & 7)) << 3));
      }
#pragma unroll
    for (int ks = 0; ks < 2; ++ks)
#pragma unroll
      for (int i = 0; i < 4; ++i)
#pragma unroll
        for (int j = 0; j < 4; ++j)
          acc[i][j] = __builtin_amdgcn_mfma_f32_16x16x32_bf16(
              af[ks][i], bf[ks][j], acc[i][j], 0, 0, 0);
  }

  // D layout: row=(lane>>4)*4+reg, col=lane&15 (verified m89/m91)
  const int col_l = lane & 15;
  const int row_l = (lane >> 4) << 2;

  if (mode == 0 || (mode == 1 && *gate != 1.0f)) {
#pragma unroll
    for (int j = 0; j < 4; ++j) {
      const long col = n0 + j * 16 + col_l;
      const float bv = bias ? bias[col] : 0.0f;
#pragma unroll
      for (int i = 0; i < 4; ++i)
#pragma unroll
        for (int r = 0; r < 4; ++r)
          Cf[(m0 + i * 16 + row_l + r) * N + col] = acc[i][j][r] + bv;
    }
  }
  if (mode == 2) {
#pragma unroll
    for (int j = 0; j < 4; ++j) {
      const long col = n0 + j * 16 + col_l;
      const float bv = bias ? bias[col] : 0.0f;
#pragma unroll
      for (int i = 0; i < 4; ++i)
#pragma unroll
        for (int r = 0; r < 4; ++r)
          Cb[(m0 + i * 16 + row_l + r) * N + col] =
              __float2bfloat16(fmaxf(acc[i][j][r] + bv, 0.0f));
    }
  }
  if (mode == 1) {
    // transpose acc tile (with bias) through LDS, then cumprod-of-cos per
    // 8-wide head group. Single wave: DS pipe is in-order per wave; the
    // lgkmcnt(0) fence pins compiler ordering + completion before the
    // cross-lane reads.
    float* shf = (float*)sh;   // 64x64 fp32 = 16 KB, exactly As+Bs
    WAIT_LGKM0();              // last K-tile's ds_reads retired before reuse
#pragma unroll
    for (int j = 0; j < 4; ++j) {
      const long col = n0 + j * 16 + col_l;
      const float bv = bias ? bias[col] : 0.0f;
#pragma unroll
      for (int i = 0; i < 4; ++i)
#pragma unroll
        for (int r = 0; r < 4; ++r)
          shf[(i * 16 + row_l + r) * 64 + j * 16 + col_l] = acc[i][j][r] + bv;
    }
    WAIT_LGKM0();              // transpose writes visible before cross-lane reads
    float th[8];
#pragma unroll
    for (int i = 0; i < 8; ++i) th[i] = theta[i];
#pragma unroll
    for (int t = 0; t < 8; ++t) {
      const int gidx = t * 64 + lane;
      const int row = gidx >> 3;        // 0..63
      const int hh = gidx & 7;          // head within tile
      const float* src = shf + row * 64 + hh * 8;
      float c[8];
#pragma unroll
      for (int i = 0; i < 8; ++i) c[i] = __cosf(src[i] + th[i]);
      float o[8];
      float p = c[1];
#pragma unroll
      for (int i = 2; i < 8; ++i) p *= c[i];
      o[0] = p;
      float cp = c[0];
#pragma unroll
      for (int i = 1; i < 8; ++i) { cp *= c[i]; o[i] = cp; }
      union { unsigned short u16[8]; uint4 v; } pk;
#pragma unroll
      for (int i = 0; i < 8; ++i) pk.u16[i] = f2bf_bits(o[i]);
      *(uint4*)(mixout + (m0 + row) * N + n0 + hh * 8) = pk.v;
    }
  }
}

// ---------------------------------------------------------------------------
// one-launch input prep: fp32->bf16 for x, Wq, Wo, W2; W1 -> bf16 padded to
// K=64 (cols 8..63 zero); conditional Wk/Wv when *gateA != 1.
// ---------------------------------------------------------------------------
__device__ __forceinline__ void cvt_one(const float* s, __hip_bfloat16* d, int n,
                                        long tid, long stride) {
  const int n4 = n >> 2;
  for (long i = tid; i < n4; i += stride) {
    float4 v = ((const float4*)s)[i];
    ushort4 u;
    u.x = f2bf_bits(v.x); u.y = f2bf_bits(v.y);
    u.z = f2bf_bits(v.z); u.w = f2bf_bits(v.w);
    ((ushort4*)d)[i] = u;
  }
}

__global__ __launch_bounds__(256) void prep_inputs(
    const float* x, __hip_bfloat16* x_bf,
    const float* Wq, __hip_bfloat16* Wq_bf,
    const float* Wo, __hip_bfloat16* Wo_bf,
    const float* W2, __hip_bfloat16* W2_bf,
    const float* W1, __hip_bfloat16* W1_pad,
    const float* Wk, __hip_bfloat16* Wk_bf,
    const float* Wv, __hip_bfloat16* Wv_bf,
    const float* gateA)
{
  const long stride = (long)gridDim.x * blockDim.x;
  const long tid = (long)blockIdx.x * blockDim.x + threadIdx.x;
  cvt_one(x, x_bf, 4096 * 512, tid, stride);
  cvt_one(Wq, Wq_bf, 512 * 512, tid, stride);
  cvt_one(Wo, Wo_bf, 512 * 512, tid, stride);
  cvt_one(W2, W2_bf, 512 * 2048, tid, stride);
  // W1: 2048x8 -> 2048x64 bf16, zero-padded. ushort4 groups: 2048*16.
  for (long g = tid; g < 2048 * 16; g += stride) {
    const int row = g >> 4;
    const int c4 = (g & 15) << 2;
    ushort4 u = {0, 0, 0, 0};
    if (c4 < 8) {
      float4 v = *(const float4*)(W1 + row * 8 + c4);
      u.x = f2bf_bits(v.x); u.y = f2bf_bits(v.y);
      u.z = f2bf_bits(v.z); u.w = f2bf_bits(v.w);
    }
    ((ushort4*)W1_pad)[g] = u;
  }
  if (*gateA != 1.0f) {
    cvt_one(Wk, Wk_bf, 512 * 512, tid, stride);
    cvt_one(Wv, Wv_bf, 512 * 512, tid, stride);
  }
}

// ---------------------------------------------------------------------------
// x1 = LN(x + attn); qm_pad[row,0:64] = [cos(x1[0:8])*cos(phi), 0...] bf16;
// conditional xs_pad[row,0:64] = [x1[0:8], 0...] bf16 when *gateF != 1.
// ---------------------------------------------------------------------------
__global__ __launch_bounds__(256) void lnffn(
    const float* __restrict__ x, const float* __restrict__ attn,
    const float* __restrict__ w, const float* __restrict__ bias,
    float* __restrict__ x1, const float* __restrict__ phi,
    __hip_bfloat16* __restrict__ qm_pad, __hip_bfloat16* __restrict__ xs_pad,
    const float* __restrict__ gateF)
{
  const int row = blockIdx.x;
  const int tid = threadIdx.x;
  const long base = (long)row * 512;
  const int c0 = tid * 2;
  float2 av = *(const float2*)(x + base + c0);
  float2 bv = *(const float2*)(attn + base + c0);
  float s0 = av.x + bv.x, s1 = av.y + bv.y;
  float sum = s0 + s1, ssq = s0 * s0 + s1 * s1;
#pragma unroll
  for (int off = 32; off > 0; off >>= 1) {
    sum += __shfl_down(sum, off);
    ssq += __shfl_down(ssq, off);
  }
  __shared__ float red[8];
  __shared__ float qtmp[8];
  const int wv = tid >> 6, ln = tid & 63;
  if (ln == 0) { red[wv] = sum; red[4 + wv] = ssq; }
  __syncthreads();
  if (tid == 0) {
    float ts = red[0] + red[1] + red[2] + red[3];
    float tq = red[4] + red[5] + red[6] + red[7];
    float mean = ts * (1.0f / 512.0f);
    float var = tq * (1.0f / 512.0f) - mean * mean;
    red[0] = mean;
    red[1] = rsqrtf(fmaxf(var, 0.0f) + 1e-5f);
  }
  __syncthreads();
  const float mean = red[0], rstd = red[1];
  const float o0 = (s0 - mean) * rstd * w[c0] + bias[c0];
  const float o1 = (s1 - mean) * rstd * w[c0 + 1] + bias[c0 + 1];
  float2 ov; ov.x = o0; ov.y = o1;
  *(float2*)(x1 + base + c0) = ov;
  if (c0 < 8) { qtmp[c0] = o0; qtmp[c0 + 1] = o1; }
  __syncthreads();
  const float gf = *gateF;
  if (tid < 32) {
    ushort2 q = {0, 0};
    if (c0 < 8) {
      q.x = f2bf_bits(__cosf(qtmp[c0]) * __cosf(phi[c0]));
      q.y = f2bf_bits(__cosf(qtmp[c0 + 1]) * __cosf(phi[c0 + 1]));
    }
    *(ushort2*)(qm_pad + (long)row * 64 + c0) = q;
    if (gf != 1.0f) {
      ushort2 xs = {0, 0};
      if (c0 < 8) { xs.x = f2bf_bits(qtmp[c0]); xs.y = f2bf_bits(qtmp[c0 + 1]); }
      *(ushort2*)(xs_pad + (long)row * 64 + c0) = xs;
    }
  }
}

// ---------------------------------------------------------------------------
// out = LayerNorm(a + mix(b, b_alt; gate)) * w + bias, row length 512.
// ---------------------------------------------------------------------------
__global__ __launch_bounds__(256) void add_ln2(
    const float* __restrict__ a, const float* __restrict__ b,
    const float* __restrict__ b_alt, const float* __restrict__ gate,
    const float* __restrict__ w, const float* __restrict__ bias,
    float* __restrict__ out)
{
  const int row = blockIdx.x;
  const int tid = threadIdx.x;
  const long base = (long)row * 512;
  const int c0 = tid * 2;
  float2 av = *(const float2*)(a + base + c0);
  float2 bv = *(const float2*)(b + base + c0);
  float s0, s1;
  const float gv = *gate;
  if (gv != 1.0f) {
    float2 cv = *(const float2*)(b_alt + base + c0);
    s0 = av.x + gv * bv.x + (1.0f - gv) * cv.x;
    s1 = av.y + gv * bv.y + (1.0f - gv) * cv.y;
  } else {
    s0 = av.x + bv.x;
    s1 = av.y + bv.y;
  }
  float sum = s0 + s1, ssq = s0 * s0 + s1 * s1;
#pragma unroll
  for (int off = 32; off > 0; off >>= 1) {
    sum += __shfl_down(sum, off);
    ssq += __shfl_down(ssq, off);
  }
  __shared__ float red[8];
  const int wv = tid >> 6, ln = tid & 63;
  if (ln == 0) { red[wv] = sum; red[4 + wv] = ssq; }
  __syncthreads();
  if (tid == 0) {
    float ts = red[0] + red[1] + red[2] + red[3];
    float tq = red[4] + red[5] + red[6] + red[7];
    float mean = ts * (1.0f / 512.0f);
    float var = tq * (1.0f / 512.0f) - mean * mean;
    red[0] = mean;
    red[1] = rsqrtf(fmaxf(var, 0.0f) + 1e-5f);
  }
  __syncthreads();
  const float mean = red[0], rstd = red[1];
  float2 ov;
  ov.x = (s0 - mean) * rstd * w[c0] + bias[c0];
  ov.y = (s1 - mean) * rstd * w[c0 + 1] + bias[c0 + 1];
  *(float2*)(out + base + c0) = ov;
}

// ---------------------------------------------------------------------------
// conditional: mix = g*quantum + (1-g)*classical (quantum already in mix).
// ---------------------------------------------------------------------------
__global__ __launch_bounds__(256) void mixfix(
    __hip_bfloat16* __restrict__ mix, const float* __restrict__ cls,
    const float* __restrict__ gate, int n)
{
  const float g = *gate;
  if (g == 1.0f) return;
  const long stride = (long)gridDim.x * blockDim.x;
  for (long i = (long)blockIdx.x * blockDim.x + threadIdx.x; i < n; i += stride) {
    float q = __bfloat162float(mix[i]);
    mix[i] = __float2bfloat16(g * q + (1.0f - g) * cls[i]);
  }
}

// ---------------------------------------------------------------------------
// Classical softmax attention fallback (only runs when gate_attn != 1).
// ---------------------------------------------------------------------------
__global__ __launch_bounds__(256) void attn_classical(
    const float* __restrict__ Q, const float* __restrict__ Kb,
    const float* __restrict__ Vb, float* __restrict__ cls,
    const float* __restrict__ skipgate)
{
  if (*skipgate == 1.0f) return;
  const int idx = blockIdx.x * blockDim.x + threadIdx.x;
  if (idx >= 4 * 64 * 1024) return;
  const int s = idx & 1023;
  const int h = (idx >> 10) & 63;
  const int b = idx >> 16;
  const long qoff = ((long)(b * 1024 + s)) * 512 + h * 8;
  float q[8];
#pragma unroll
  for (int i = 0; i < 8; ++i) q[i] = Q[qoff + i] * 0.35355339059327373f;
  float m = -INFINITY, l = 0.0f, acc[8];
#pragma unroll
  for (int i = 0; i < 8; ++i) acc[i] = 0.0f;
  for (int t = 0; t < 1024; ++t) {
    const long koff = ((long)(b * 1024 + t)) * 512 + h * 8;
    const float* kr = Kb + koff;
    const float* vr = Vb + koff;
    float sc = 0.0f;
#pragma unroll
    for (int i = 0; i < 8; ++i) sc += q[i] * kr[i];
    float nm = fmaxf(m, sc);
    float corr = __expf(m - nm);
    float p = __expf(sc - nm);
    l = l * corr + p;
#pragma unroll
    for (int i = 0; i < 8; ++i) acc[i] = acc[i] * corr + p * vr[i];
    m = nm;
  }
  const float inv = 1.0f / l;
#pragma unroll
  for (int i = 0; i < 8; ++i) cls[qoff + i] = acc[i] * inv;
}

// ---------------------------------------------------------------------------
extern "C" void kernel_launch(void* const* d_in, const int* in_sizes, int n_in,
                              void* d_out, int out_size, void* d_ws, size_t ws_size,
                              hipStream_t stream) {
  const float* x     = (const float*)d_in[0];
  const float* Wq    = (const float*)d_in[1];
  const float* bq    = (const float*)d_in[2];
  const float* Wk    = (const float*)d_in[3];
  const float* bk    = (const float*)d_in[4];
  const float* Wv    = (const float*)d_in[5];
  const float* bv    = (const float*)d_in[6];
  const float* theta = (const float*)d_in[7];
  const float* gateA = (const float*)d_in[8];
  const float* Wo    = (const float*)d_in[9];
  const float* bo    = (const float*)d_in[10];
  const float* ln1w  = (const float*)d_in[11];
  const float* ln1b  = (const float*)d_in[12];
  const float* W1    = (const float*)d_in[13];
  const float* b1    = (const float*)d_in[14];
  const float* W2    = (const float*)d_in[15];
  const float* b2    = (const float*)d_in[16];
  const float* phi   = (const float*)d_in[17];
  const float* gateF = (const float*)d_in[18];
  const float* ln2w  = (const float*)d_in[19];
  const float* ln2b  = (const float*)d_in[20];
  float* out = (float*)d_out;

  const size_t MB = 1024 * 1024;
  char* wsb = (char*)d_ws;
  __hip_bfloat16* x_bf   = (__hip_bfloat16*)(wsb + 0 * MB);            // 4 MB
  __hip_bfloat16* Wq_bf  = (__hip_bfloat16*)(wsb + 4 * MB);            // 0.5 MB
  __hip_bfloat16* Wo_bf  = (__hip_bfloat16*)(wsb + 4 * MB + 512 * 1024);
  __hip_bfloat16* W2_bf  = (__hip_bfloat16*)(wsb + 5 * MB);            // 2 MB
  __hip_bfloat16* W1_pad = (__hip_bfloat16*)(wsb + 7 * MB);            // 256 KB
  __hip_bfloat16* qm_pad = (__hip_bfloat16*)(wsb + 7 * MB + 512 * 1024); // 512 KB
  __hip_bfloat16* mix_bf = (__hip_bfloat16*)(wsb + 8 * MB);            // 4 MB
  float*          attn   = (float*)(wsb + 12 * MB);                    // 8 MB
  float*          x1     = (float*)(wsb + 20 * MB);                    // 8 MB
  __hip_bfloat16* hq_bf  = (__hip_bfloat16*)(wsb + 28 * MB);           // 16 MB
  float*          Fb     = (float*)(wsb + 44 * MB);                    // 8 MB
  // conditional (gate != 1) buffers
  float*          Qb     = (float*)(wsb + 52 * MB);                    // 8 MB
  __hip_bfloat16* Wk_bf  = (__hip_bfloat16*)(wsb + 60 * MB);
  __hip_bfloat16* Wv_bf  = (__hip_bfloat16*)(wsb + 60 * MB + 512 * 1024);
  float*          Kb2    = (float*)(wsb + 61 * MB);                    // 8 MB
  float*          Vb2    = (float*)(wsb + 69 * MB);                    // 8 MB
  float*          clsb   = (float*)(wsb + 77 * MB);                    // 8 MB
  __hip_bfloat16* xs_pad = (__hip_bfloat16*)(wsb + 85 * MB);           // 512 KB
  __hip_bfloat16* hc_bf  = (__hip_bfloat16*)(wsb + 86 * MB);           // 16 MB
  float*          Fc     = (float*)(wsb + 102 * MB);                   // 8 MB

  // 1. input prep (all conversions, one launch)
  prep_inputs<<<1024, 256, 0, stream>>>(
      x, x_bf, Wq, Wq_bf, Wo, Wo_bf, W2, W2_bf, W1, W1_pad,
      Wk, Wk_bf, Wv, Wv_bf, gateA);
  // 2. Q GEMM + fused quantum epilogue -> mix_bf (+ Qb fp32 when gateA!=1)
  gemm64<<<dim3(64, 8), 64, 0, stream>>>(
      x_bf, Wq_bf, nullptr, bq, nullptr, Qb, nullptr, nullptr,
      4096, 512, 512, 1, theta, gateA, mix_bf, nullptr);
  // 3. [cond] K/V projections, batched via z
  gemm64<<<dim3(64, 8, 2), 64, 0, stream>>>(
      x_bf, Wk_bf, Wv_bf, bk, bv, Kb2, Vb2, nullptr,
      4096, 512, 512, 0, nullptr, nullptr, nullptr, gateA);
  // 4. [cond] classical softmax attention
  attn_classical<<<1024, 256, 0, stream>>>(Qb, Kb2, Vb2, clsb, gateA);
  // 5. [cond] blend quantum with classical
  mixfix<<<512, 256, 0, stream>>>(mix_bf, clsb, gateA, 4096 * 512);
  // 6. attn_out = mix @ Wo^T + bo
  gemm64<<<dim3(64, 8), 64, 0, stream>>>(
      mix_bf, Wo_bf, nullptr, bo, nullptr, attn, nullptr, nullptr,
      4096, 512, 512, 0, nullptr, nullptr, nullptr, nullptr);
  // 7. x1 = LN(x + attn); qm_pad (+ xs_pad cond)
  lnffn<<<4096, 256, 0, stream>>>(x, attn, ln1w, ln1b, x1, phi,
                                  qm_pad, xs_pad, gateF);
  // 8. hq = relu(qm_pad @ W1_pad^T + b1) -> bf16 (MFMA, K=64 padded)
  gemm64<<<dim3(64, 32), 64, 0, stream>>>(
      qm_pad, W1_pad, nullptr, b1, nullptr, nullptr, nullptr, hq_bf,
      4096, 2048, 64, 2, nullptr, nullptr, nullptr, nullptr);
  // 9. [cond] hc = relu(xs_pad @ W1_pad^T + b1) -> bf16
  gemm64<<<dim3(64, 32), 64, 0, stream>>>(
      xs_pad, W1_pad, nullptr, b1, nullptr, nullptr, nullptr, hc_bf,
      4096, 2048, 64, 2, nullptr, nullptr, nullptr, gateF);
  // 10. F = hq @ W2^T + b2
  gemm64<<<dim3(64, 8), 64, 0, stream>>>(
      hq_bf, W2_bf, nullptr, b2, nullptr, Fb, nullptr, nullptr,
      4096, 512, 2048, 0, nullptr, nullptr, nullptr, nullptr);
  // 11. [cond] Fc = hc @ W2^T + b2
  gemm64<<<dim3(64, 8), 64, 0, stream>>>(
      hc_bf, W2_bf, nullptr, b2, nullptr, Fc, nullptr, nullptr,
      4096, 512, 2048, 0, nullptr, nullptr, nullptr, gateF);
  // 12. out = LN(x1 + gF*F + (1-gF)*Fc)
  add_ln2<<<4096, 256, 0, stream>>>(x1, Fb, Fc, gateF, ln2w, ln2b, out);
}

// Round 5
// 175.181 us; speedup vs baseline: 1.0993x; 1.0993x over previous
//
#include <hip/hip_runtime.h>
#include <hip/hip_bf16.h>

// Shapes fixed by the problem:
// B=4, S=1024, D=512, H=64, DK=8, FF=2048, NQ=8. Mtok = B*S = 4096.

typedef short short8 __attribute__((ext_vector_type(8)));
typedef float floatx4 __attribute__((ext_vector_type(4)));

__device__ __forceinline__ unsigned short f2bf_bits(float f) {
  __hip_bfloat16 h = __float2bfloat16(f);
  return *reinterpret_cast<unsigned short*>(&h);
}

#define GLOBAL_LOAD_LDS16(g, l)                                               \
  __builtin_amdgcn_global_load_lds(                                           \
      (const __attribute__((address_space(1))) void*)(g),                     \
      (__attribute__((address_space(3))) void*)(l), 16, 0, 0)

// Compiler does NOT model global_load_lds's LDS write as aliasing later LDS
// reads (round-3 NaN). Explicit waits, memory clobber pins ordering.
#define WAIT_VMCNT0()   asm volatile("s_waitcnt vmcnt(0)" ::: "memory")
#define WAIT_VMCNT16()  asm volatile("s_waitcnt vmcnt(16)" ::: "memory")
#define WAIT_LGKM0()    asm volatile("s_waitcnt lgkmcnt(0)" ::: "memory")

// ---------------------------------------------------------------------------
// Single-wave GEMM: C[M,N] = A[M,K] @ W[N,K]^T + bias[N].
// Block = 64 threads = 1 wave computing a 64x64 tile via 4x4 of 16x16x32
// MFMA, BK=64. Double-buffered LDS staging: while computing tile t, tile
// t+1's 16 global_load_lds are in flight; s_waitcnt vmcnt(16) waits only
// for the current buffer's loads (16 oldest), hiding load latency with
// MFMA+ds_read of the current tile (round-4 lesson: grid gives only 2
// single-wave blocks/CU, so latency must be hidden by ILP, not TLP).
// Staging: XOR chunk swizzle (phys chunk p of row r holds logical chunk
// p ^ (r&7)) -> conflict-free ds_read_b128 fragments.
// modes: 0 = fp32 store (acc+bias)
//        1 = quantum epilogue: LDS-transpose acc, o = cumprod-of-cos with
//            z0 head element, store bf16 to mixout. If *gate != 1, also
//            store plain fp32 (acc+bias) to Cf for the classical path.
//        2 = bf16 store of relu(acc+bias) to Cb.
// blockIdx.z batching (for K/V): z==1 uses Wb/biasb/Cfb.
// Whole grid early-exits when *skipgate == 1.0f.
// ---------------------------------------------------------------------------
__global__ __launch_bounds__(64) void gemm64(
    const __hip_bfloat16* __restrict__ A,
    const __hip_bfloat16* __restrict__ W,
    const __hip_bfloat16* __restrict__ Wb,
    const float* __restrict__ bias,
    const float* __restrict__ biasb,
    float* __restrict__ Cf,
    float* __restrict__ Cfb,
    __hip_bfloat16* __restrict__ Cb,
    int M, int N, int K, int mode,
    const float* __restrict__ theta,
    const float* __restrict__ gate,
    __hip_bfloat16* __restrict__ mixout,
    const float* __restrict__ skipgate)
{
  if (skipgate != nullptr && *skipgate == 1.0f) return;
  if (blockIdx.z == 1) { W = Wb; bias = biasb; Cf = Cfb; }
  // 32 KB: two ping-pong buffers, each As(4096 bf16) + Bs(4096 bf16)
  __shared__ __align__(16) __hip_bfloat16 sh[16384];
  const int lane = threadIdx.x;
  const long m0 = (long)blockIdx.x * 64;
  const long n0 = (long)blockIdx.y * 64;

  floatx4 acc[4][4];
#pragma unroll
  for (int i = 0; i < 4; ++i)
#pragma unroll
    for (int j = 0; j < 4; ++j)
      acc[i][j] = (floatx4){0.f, 0.f, 0.f, 0.f};

  const int srow = lane >> 3;       // 0..7: row within 8-row staging block
  const int schunk = lane & 7;      // physical 16B chunk
  const int gchunk = schunk ^ srow; // logical chunk (row&7 == srow)
  const int frow = lane & 15;
  const int fk = lane >> 4;         // 0..3

  auto stage = [&](int kt, __hip_bfloat16* Ab, __hip_bfloat16* Bb) {
#pragma unroll
    for (int ib = 0; ib < 8; ++ib) {
      const int row = ib * 8 + srow;
      GLOBAL_LOAD_LDS16(A + (m0 + row) * K + kt + gchunk * 8, Ab + ib * 512);
      GLOBAL_LOAD_LDS16(W + (n0 + row) * K + kt + gchunk * 8, Bb + ib * 512);
    }
  };

  const int ntiles = K >> 6;
  stage(0, sh, sh + 4096);                 // preload tile 0 -> buf 0
  for (int t = 0; t < ntiles; ++t) {
    __hip_bfloat16* As = sh + (t & 1) * 8192;
    __hip_bfloat16* Bs = As + 4096;
    if (t + 1 < ntiles) {
      // prior iteration's ds_reads from the other buffer retired before
      // its LDS is overwritten by the new DMA
      WAIT_LGKM0();
      __hip_bfloat16* An = sh + ((t + 1) & 1) * 8192;
      stage((t + 1) << 6, An, An + 4096);
      // wait for current buffer's 16 loads only; next tile's 16 stay in
      // flight across the ds_read+MFMA phase below
      WAIT_VMCNT16();
    } else {
      WAIT_VMCNT0();
    }
    short8 af[2][4], bf[2][4];
#pragma unroll
    for (int ks = 0; ks < 2; ++ks)
#pragma unroll
      for (int i = 0; i < 4; ++i) {
        const int ar = i * 16 + frow;
        af[ks][i] = *(const short8*)(As + ar * 64 + (((ks * 4 + fk) ^ (ar & 7)) << 3));
        bf[ks][i] = *(const short8*)(Bs + ar * 64 + (((ks * 4 + fk) ^ (ar & 7)) << 3));
      }
#pragma unroll
    for (int ks = 0; ks < 2; ++ks)
#pragma unroll
      for (int i = 0; i < 4; ++i)
#pragma unroll
        for (int j = 0; j < 4; ++j)
          acc[i][j] = __builtin_amdgcn_mfma_f32_16x16x32_bf16(
              af[ks][i], bf[ks][j], acc[i][j], 0, 0, 0);
  }

  // D layout: row=(lane>>4)*4+reg, col=lane&15 (verified m89/m91)
  const int col_l = lane & 15;
  const int row_l = (lane >> 4) << 2;

  if (mode == 0 || (mode == 1 && *gate != 1.0f)) {
#pragma unroll
    for (int j = 0; j < 4; ++j) {
      const long col = n0 + j * 16 + col_l;
      const float bv = bias ? bias[col] : 0.0f;
#pragma unroll
      for (int i = 0; i < 4; ++i)
#pragma unroll
        for (int r = 0; r < 4; ++r)
          Cf[(m0 + i * 16 + row_l + r) * N + col] = acc[i][j][r] + bv;
    }
  }
  if (mode == 2) {
#pragma unroll
    for (int j = 0; j < 4; ++j) {
      const long col = n0 + j * 16 + col_l;
      const float bv = bias ? bias[col] : 0.0f;
#pragma unroll
      for (int i = 0; i < 4; ++i)
#pragma unroll
        for (int r = 0; r < 4; ++r)
          Cb[(m0 + i * 16 + row_l + r) * N + col] =
              __float2bfloat16(fmaxf(acc[i][j][r] + bv, 0.0f));
    }
  }
  if (mode == 1) {
    // transpose acc tile (with bias) through LDS, then cumprod-of-cos per
    // 8-wide head group. Single wave: DS pipe is in-order per wave; the
    // lgkmcnt(0) fence pins compiler ordering + completion.
    float* shf = (float*)sh;   // 64x64 fp32 = 16 KB (first buffer pair)
    WAIT_LGKM0();              // last K-tile's ds_reads retired before reuse
#pragma unroll
    for (int j = 0; j < 4; ++j) {
      const long col = n0 + j * 16 + col_l;
      const float bv = bias ? bias[col] : 0.0f;
#pragma unroll
      for (int i = 0; i < 4; ++i)
#pragma unroll
        for (int r = 0; r < 4; ++r)
          shf[(i * 16 + row_l + r) * 64 + j * 16 + col_l] = acc[i][j][r] + bv;
    }
    WAIT_LGKM0();              // transpose writes visible before cross-lane reads
    float th[8];
#pragma unroll
    for (int i = 0; i < 8; ++i) th[i] = theta[i];
#pragma unroll
    for (int t = 0; t < 8; ++t) {
      const int gidx = t * 64 + lane;
      const int row = gidx >> 3;        // 0..63
      const int hh = gidx & 7;          // head within tile
      const float* src = shf + row * 64 + hh * 8;
      float c[8];
#pragma unroll
      for (int i = 0; i < 8; ++i) c[i] = __cosf(src[i] + th[i]);
      float o[8];
      float p = c[1];
#pragma unroll
      for (int i = 2; i < 8; ++i) p *= c[i];
      o[0] = p;
      float cp = c[0];
#pragma unroll
      for (int i = 1; i < 8; ++i) { cp *= c[i]; o[i] = cp; }
      union { unsigned short u16[8]; uint4 v; } pk;
#pragma unroll
      for (int i = 0; i < 8; ++i) pk.u16[i] = f2bf_bits(o[i]);
      *(uint4*)(mixout + (m0 + row) * N + n0 + hh * 8) = pk.v;
    }
  }
}

// ---------------------------------------------------------------------------
// one-launch input prep: fp32->bf16 for x, Wq, Wo, W2; W1 -> bf16 padded to
// K=64 (cols 8..63 zero); conditional Wk/Wv when *gateA != 1.
// ---------------------------------------------------------------------------
__device__ __forceinline__ void cvt_one(const float* s, __hip_bfloat16* d, int n,
                                        long tid, long stride) {
  const int n4 = n >> 2;
  for (long i = tid; i < n4; i += stride) {
    float4 v = ((const float4*)s)[i];
    ushort4 u;
    u.x = f2bf_bits(v.x); u.y = f2bf_bits(v.y);
    u.z = f2bf_bits(v.z); u.w = f2bf_bits(v.w);
    ((ushort4*)d)[i] = u;
  }
}

__global__ __launch_bounds__(256) void prep_inputs(
    const float* x, __hip_bfloat16* x_bf,
    const float* Wq, __hip_bfloat16* Wq_bf,
    const float* Wo, __hip_bfloat16* Wo_bf,
    const float* W2, __hip_bfloat16* W2_bf,
    const float* W1, __hip_bfloat16* W1_pad,
    const float* Wk, __hip_bfloat16* Wk_bf,
    const float* Wv, __hip_bfloat16* Wv_bf,
    const float* gateA)
{
  const long stride = (long)gridDim.x * blockDim.x;
  const long tid = (long)blockIdx.x * blockDim.x + threadIdx.x;
  cvt_one(x, x_bf, 4096 * 512, tid, stride);
  cvt_one(Wq, Wq_bf, 512 * 512, tid, stride);
  cvt_one(Wo, Wo_bf, 512 * 512, tid, stride);
  cvt_one(W2, W2_bf, 512 * 2048, tid, stride);
  // W1: 2048x8 -> 2048x64 bf16, zero-padded. ushort4 groups: 2048*16.
  for (long g = tid; g < 2048 * 16; g += stride) {
    const int row = g >> 4;
    const int c4 = (g & 15) << 2;
    ushort4 u = {0, 0, 0, 0};
    if (c4 < 8) {
      float4 v = *(const float4*)(W1 + row * 8 + c4);
      u.x = f2bf_bits(v.x); u.y = f2bf_bits(v.y);
      u.z = f2bf_bits(v.z); u.w = f2bf_bits(v.w);
    }
    ((ushort4*)W1_pad)[g] = u;
  }
  if (*gateA != 1.0f) {
    cvt_one(Wk, Wk_bf, 512 * 512, tid, stride);
    cvt_one(Wv, Wv_bf, 512 * 512, tid, stride);
  }
}

// ---------------------------------------------------------------------------
// x1 = LN(x + attn); qm_pad[row,0:64] = [cos(x1[0:8])*cos(phi), 0...] bf16;
// conditional xs_pad[row,0:64] = [x1[0:8], 0...] bf16 when *gateF != 1.
// ---------------------------------------------------------------------------
__global__ __launch_bounds__(256) void lnffn(
    const float* __restrict__ x, const float* __restrict__ attn,
    const float* __restrict__ w, const float* __restrict__ bias,
    float* __restrict__ x1, const float* __restrict__ phi,
    __hip_bfloat16* __restrict__ qm_pad, __hip_bfloat16* __restrict__ xs_pad,
    const float* __restrict__ gateF)
{
  const int row = blockIdx.x;
  const int tid = threadIdx.x;
  const long base = (long)row * 512;
  const int c0 = tid * 2;
  float2 av = *(const float2*)(x + base + c0);
  float2 bv = *(const float2*)(attn + base + c0);
  float s0 = av.x + bv.x, s1 = av.y + bv.y;
  float sum = s0 + s1, ssq = s0 * s0 + s1 * s1;
#pragma unroll
  for (int off = 32; off > 0; off >>= 1) {
    sum += __shfl_down(sum, off);
    ssq += __shfl_down(ssq, off);
  }
  __shared__ float red[8];
  __shared__ float qtmp[8];
  const int wv = tid >> 6, ln = tid & 63;
  if (ln == 0) { red[wv] = sum; red[4 + wv] = ssq; }
  __syncthreads();
  if (tid == 0) {
    float ts = red[0] + red[1] + red[2] + red[3];
    float tq = red[4] + red[5] + red[6] + red[7];
    float mean = ts * (1.0f / 512.0f);
    float var = tq * (1.0f / 512.0f) - mean * mean;
    red[0] = mean;
    red[1] = rsqrtf(fmaxf(var, 0.0f) + 1e-5f);
  }
  __syncthreads();
  const float mean = red[0], rstd = red[1];
  const float o0 = (s0 - mean) * rstd * w[c0] + bias[c0];
  const float o1 = (s1 - mean) * rstd * w[c0 + 1] + bias[c0 + 1];
  float2 ov; ov.x = o0; ov.y = o1;
  *(float2*)(x1 + base + c0) = ov;
  if (c0 < 8) { qtmp[c0] = o0; qtmp[c0 + 1] = o1; }
  __syncthreads();
  const float gf = *gateF;
  if (tid < 32) {
    ushort2 q = {0, 0};
    if (c0 < 8) {
      q.x = f2bf_bits(__cosf(qtmp[c0]) * __cosf(phi[c0]));
      q.y = f2bf_bits(__cosf(qtmp[c0 + 1]) * __cosf(phi[c0 + 1]));
    }
    *(ushort2*)(qm_pad + (long)row * 64 + c0) = q;
    if (gf != 1.0f) {
      ushort2 xs = {0, 0};
      if (c0 < 8) { xs.x = f2bf_bits(qtmp[c0]); xs.y = f2bf_bits(qtmp[c0 + 1]); }
      *(ushort2*)(xs_pad + (long)row * 64 + c0) = xs;
    }
  }
}

// ---------------------------------------------------------------------------
// out = LayerNorm(a + mix(b, b_alt; gate)) * w + bias, row length 512.
// ---------------------------------------------------------------------------
__global__ __launch_bounds__(256) void add_ln2(
    const float* __restrict__ a, const float* __restrict__ b,
    const float* __restrict__ b_alt, const float* __restrict__ gate,
    const float* __restrict__ w, const float* __restrict__ bias,
    float* __restrict__ out)
{
  const int row = blockIdx.x;
  const int tid = threadIdx.x;
  const long base = (long)row * 512;
  const int c0 = tid * 2;
  float2 av = *(const float2*)(a + base + c0);
  float2 bv = *(const float2*)(b + base + c0);
  float s0, s1;
  const float gv = *gate;
  if (gv != 1.0f) {
    float2 cv = *(const float2*)(b_alt + base + c0);
    s0 = av.x + gv * bv.x + (1.0f - gv) * cv.x;
    s1 = av.y + gv * bv.y + (1.0f - gv) * cv.y;
  } else {
    s0 = av.x + bv.x;
    s1 = av.y + bv.y;
  }
  float sum = s0 + s1, ssq = s0 * s0 + s1 * s1;
#pragma unroll
  for (int off = 32; off > 0; off >>= 1) {
    sum += __shfl_down(sum, off);
    ssq += __shfl_down(ssq, off);
  }
  __shared__ float red[8];
  const int wv = tid >> 6, ln = tid & 63;
  if (ln == 0) { red[wv] = sum; red[4 + wv] = ssq; }
  __syncthreads();
  if (tid == 0) {
    float ts = red[0] + red[1] + red[2] + red[3];
    float tq = red[4] + red[5] + red[6] + red[7];
    float mean = ts * (1.0f / 512.0f);
    float var = tq * (1.0f / 512.0f) - mean * mean;
    red[0] = mean;
    red[1] = rsqrtf(fmaxf(var, 0.0f) + 1e-5f);
  }
  __syncthreads();
  const float mean = red[0], rstd = red[1];
  float2 ov;
  ov.x = (s0 - mean) * rstd * w[c0] + bias[c0];
  ov.y = (s1 - mean) * rstd * w[c0 + 1] + bias[c0 + 1];
  *(float2*)(out + base + c0) = ov;
}

// ---------------------------------------------------------------------------
// conditional: mix = g*quantum + (1-g)*classical (quantum already in mix).
// ---------------------------------------------------------------------------
__global__ __launch_bounds__(256) void mixfix(
    __hip_bfloat16* __restrict__ mix, const float* __restrict__ cls,
    const float* __restrict__ gate, int n)
{
  const float g = *gate;
  if (g == 1.0f) return;
  const long stride = (long)gridDim.x * blockDim.x;
  for (long i = (long)blockIdx.x * blockDim.x + threadIdx.x; i < n; i += stride) {
    float q = __bfloat162float(mix[i]);
    mix[i] = __float2bfloat16(g * q + (1.0f - g) * cls[i]);
  }
}

// ---------------------------------------------------------------------------
// Classical softmax attention fallback (only runs when gate_attn != 1).
// ---------------------------------------------------------------------------
__global__ __launch_bounds__(256) void attn_classical(
    const float* __restrict__ Q, const float* __restrict__ Kb,
    const float* __restrict__ Vb, float* __restrict__ cls,
    const float* __restrict__ skipgate)
{
  if (*skipgate == 1.0f) return;
  const int idx = blockIdx.x * blockDim.x + threadIdx.x;
  if (idx >= 4 * 64 * 1024) return;
  const int s = idx & 1023;
  const int h = (idx >> 10) & 63;
  const int b = idx >> 16;
  const long qoff = ((long)(b * 1024 + s)) * 512 + h * 8;
  float q[8];
#pragma unroll
  for (int i = 0; i < 8; ++i) q[i] = Q[qoff + i] * 0.35355339059327373f;
  float m = -INFINITY, l = 0.0f, acc[8];
#pragma unroll
  for (int i = 0; i < 8; ++i) acc[i] = 0.0f;
  for (int t = 0; t < 1024; ++t) {
    const long koff = ((long)(b * 1024 + t)) * 512 + h * 8;
    const float* kr = Kb + koff;
    const float* vr = Vb + koff;
    float sc = 0.0f;
#pragma unroll
    for (int i = 0; i < 8; ++i) sc += q[i] * kr[i];
    float nm = fmaxf(m, sc);
    float corr = __expf(m - nm);
    float p = __expf(sc - nm);
    l = l * corr + p;
#pragma unroll
    for (int i = 0; i < 8; ++i) acc[i] = acc[i] * corr + p * vr[i];
    m = nm;
  }
  const float inv = 1.0f / l;
#pragma unroll
  for (int i = 0; i < 8; ++i) cls[qoff + i] = acc[i] * inv;
}

// ---------------------------------------------------------------------------
extern "C" void kernel_launch(void* const* d_in, const int* in_sizes, int n_in,
                              void* d_out, int out_size, void* d_ws, size_t ws_size,
                              hipStream_t stream) {
  const float* x     = (const float*)d_in[0];
  const float* Wq    = (const float*)d_in[1];
  const float* bq    = (const float*)d_in[2];
  const float* Wk    = (const float*)d_in[3];
  const float* bk    = (const float*)d_in[4];
  const float* Wv    = (const float*)d_in[5];
  const float* bv    = (const float*)d_in[6];
  const float* theta = (const float*)d_in[7];
  const float* gateA = (const float*)d_in[8];
  const float* Wo    = (const float*)d_in[9];
  const float* bo    = (const float*)d_in[10];
  const float* ln1w  = (const float*)d_in[11];
  const float* ln1b  = (const float*)d_in[12];
  const float* W1    = (const float*)d_in[13];
  const float* b1    = (const float*)d_in[14];
  const float* W2    = (const float*)d_in[15];
  const float* b2    = (const float*)d_in[16];
  const float* phi   = (const float*)d_in[17];
  const float* gateF = (const float*)d_in[18];
  const float* ln2w  = (const float*)d_in[19];
  const float* ln2b  = (const float*)d_in[20];
  float* out = (float*)d_out;

  const size_t MB = 1024 * 1024;
  char* wsb = (char*)d_ws;
  __hip_bfloat16* x_bf   = (__hip_bfloat16*)(wsb + 0 * MB);            // 4 MB
  __hip_bfloat16* Wq_bf  = (__hip_bfloat16*)(wsb + 4 * MB);            // 0.5 MB
  __hip_bfloat16* Wo_bf  = (__hip_bfloat16*)(wsb + 4 * MB + 512 * 1024);
  __hip_bfloat16* W2_bf  = (__hip_bfloat16*)(wsb + 5 * MB);            // 2 MB
  __hip_bfloat16* W1_pad = (__hip_bfloat16*)(wsb + 7 * MB);            // 256 KB
  __hip_bfloat16* qm_pad = (__hip_bfloat16*)(wsb + 7 * MB + 512 * 1024); // 512 KB
  __hip_bfloat16* mix_bf = (__hip_bfloat16*)(wsb + 8 * MB);            // 4 MB
  float*          attn   = (float*)(wsb + 12 * MB);                    // 8 MB
  float*          x1     = (float*)(wsb + 20 * MB);                    // 8 MB
  __hip_bfloat16* hq_bf  = (__hip_bfloat16*)(wsb + 28 * MB);           // 16 MB
  float*          Fb     = (float*)(wsb + 44 * MB);                    // 8 MB
  // conditional (gate != 1) buffers
  float*          Qb     = (float*)(wsb + 52 * MB);                    // 8 MB
  __hip_bfloat16* Wk_bf  = (__hip_bfloat16*)(wsb + 60 * MB);
  __hip_bfloat16* Wv_bf  = (__hip_bfloat16*)(wsb + 60 * MB + 512 * 1024);
  float*          Kb2    = (float*)(wsb + 61 * MB);                    // 8 MB
  float*          Vb2    = (float*)(wsb + 69 * MB);                    // 8 MB
  float*          clsb   = (float*)(wsb + 77 * MB);                    // 8 MB
  __hip_bfloat16* xs_pad = (__hip_bfloat16*)(wsb + 85 * MB);           // 512 KB
  __hip_bfloat16* hc_bf  = (__hip_bfloat16*)(wsb + 86 * MB);           // 16 MB
  float*          Fc     = (float*)(wsb + 102 * MB);                   // 8 MB

  // 1. input prep (all conversions, one launch)
  prep_inputs<<<1024, 256, 0, stream>>>(
      x, x_bf, Wq, Wq_bf, Wo, Wo_bf, W2, W2_bf, W1, W1_pad,
      Wk, Wk_bf, Wv, Wv_bf, gateA);
  // 2. Q GEMM + fused quantum epilogue -> mix_bf (+ Qb fp32 when gateA!=1)
  gemm64<<<dim3(64, 8), 64, 0, stream>>>(
      x_bf, Wq_bf, nullptr, bq, nullptr, Qb, nullptr, nullptr,
      4096, 512, 512, 1, theta, gateA, mix_bf, nullptr);
  // 3. [cond] K/V projections, batched via z
  gemm64<<<dim3(64, 8, 2), 64, 0, stream>>>(
      x_bf, Wk_bf, Wv_bf, bk, bv, Kb2, Vb2, nullptr,
      4096, 512, 512, 0, nullptr, nullptr, nullptr, gateA);
  // 4. [cond] classical softmax attention
  attn_classical<<<1024, 256, 0, stream>>>(Qb, Kb2, Vb2, clsb, gateA);
  // 5. [cond] blend quantum with classical
  mixfix<<<512, 256, 0, stream>>>(mix_bf, clsb, gateA, 4096 * 512);
  // 6. attn_out = mix @ Wo^T + bo
  gemm64<<<dim3(64, 8), 64, 0, stream>>>(
      mix_bf, Wo_bf, nullptr, bo, nullptr, attn, nullptr, nullptr,
      4096, 512, 512, 0, nullptr, nullptr, nullptr, nullptr);
  // 7. x1 = LN(x + attn); qm_pad (+ xs_pad cond)
  lnffn<<<4096, 256, 0, stream>>>(x, attn, ln1w, ln1b, x1, phi,
                                  qm_pad, xs_pad, gateF);
  // 8. hq = relu(qm_pad @ W1_pad^T + b1) -> bf16 (MFMA, K=64 padded)
  gemm64<<<dim3(64, 32), 64, 0, stream>>>(
      qm_pad, W1_pad, nullptr, b1, nullptr, nullptr, nullptr, hq_bf,
      4096, 2048, 64, 2, nullptr, nullptr, nullptr, nullptr);
  // 9. [cond] hc = relu(xs_pad @ W1_pad^T + b1) -> bf16
  gemm64<<<dim3(64, 32), 64, 0, stream>>>(
      xs_pad, W1_pad, nullptr, b1, nullptr, nullptr, nullptr, hc_bf,
      4096, 2048, 64, 2, nullptr, nullptr, nullptr, gateF);
  // 10. F = hq @ W2^T + b2
  gemm64<<<dim3(64, 8), 64, 0, stream>>>(
      hq_bf, W2_bf, nullptr, b2, nullptr, Fb, nullptr, nullptr,
      4096, 512, 2048, 0, nullptr, nullptr, nullptr, nullptr);
  // 11. [cond] Fc = hc @ W2^T + b2
  gemm64<<<dim3(64, 8), 64, 0, stream>>>(
      hc_bf, W2_bf, nullptr, b2, nullptr, Fc, nullptr, nullptr,
      4096, 512, 2048, 0, nullptr, nullptr, nullptr, gateF);
  // 12. out = LN(x1 + gF*F + (1-gF)*Fc)
  add_ln2<<<4096, 256, 0, stream>>>(x1, Fb, Fc, gateF, ln2w, ln2b, out);
}

// Round 6
// 162.357 us; speedup vs baseline: 1.1861x; 1.0790x over previous
//
#include <hip/hip_runtime.h>
#include <hip/hip_bf16.h>

// Shapes fixed by the problem:
// B=4, S=1024, D=512, H=64, DK=8, FF=2048, NQ=8. Mtok = B*S = 4096.

typedef short short8 __attribute__((ext_vector_type(8)));
typedef float floatx4 __attribute__((ext_vector_type(4)));

__device__ __forceinline__ unsigned short f2bf_bits(float f) {
  __hip_bfloat16 h = __float2bfloat16(f);
  return *reinterpret_cast<unsigned short*>(&h);
}
__device__ __forceinline__ float bfbits2f(unsigned short u) {
  union { unsigned int u; float f; } c;
  c.u = (unsigned int)u << 16;
  return c.f;
}

#define GLOBAL_LOAD_LDS16(g, l)                                               \
  __builtin_amdgcn_global_load_lds(                                           \
      (const __attribute__((address_space(1))) void*)(g),                     \
      (__attribute__((address_space(3))) void*)(l), 16, 0, 0)

// Compiler does NOT model global_load_lds's LDS write as aliasing later LDS
// reads (round-3 NaN). Explicit waits, memory clobber pins ordering.
#define WAIT_VMCNT0()   asm volatile("s_waitcnt vmcnt(0)" ::: "memory")
#define WAIT_VMCNT16()  asm volatile("s_waitcnt vmcnt(16)" ::: "memory")
#define WAIT_LGKM0()    asm volatile("s_waitcnt lgkmcnt(0)" ::: "memory")

// ---------------------------------------------------------------------------
// Single-wave GEMM core: acc(64x64) += A[m0:,:K] @ W[n0:,:K]^T.
// 4x4 of 16x16x32 MFMA, BK=64, double-buffered LDS staging with
// s_waitcnt vmcnt(16): next tile's 16 DMA loads stay in flight across the
// current tile's ds_read+MFMA (round-4 lesson: only ~2 single-wave blocks/CU
// -> hide latency with ILP, not TLP). XOR chunk swizzle: phys 16B chunk p of
// row r holds logical chunk p ^ (r&7) -> conflict-free ds_read_b128.
// sh must be 16384 bf16 (32 KB).
// ---------------------------------------------------------------------------
__device__ __forceinline__ void gemm_core(
    const __hip_bfloat16* __restrict__ A,
    const __hip_bfloat16* __restrict__ W,
    int K, long m0, long n0, int lane,
    __hip_bfloat16* sh, floatx4 acc[4][4])
{
  const int srow = lane >> 3;
  const int schunk = lane & 7;
  const int gchunk = schunk ^ srow;
  const int frow = lane & 15;
  const int fk = lane >> 4;

  auto stage = [&](int kt, __hip_bfloat16* Ab, __hip_bfloat16* Bb) {
#pragma unroll
    for (int ib = 0; ib < 8; ++ib) {
      const int row = ib * 8 + srow;
      GLOBAL_LOAD_LDS16(A + (m0 + row) * K + kt + gchunk * 8, Ab + ib * 512);
      GLOBAL_LOAD_LDS16(W + (n0 + row) * K + kt + gchunk * 8, Bb + ib * 512);
    }
  };

  const int ntiles = K >> 6;
  stage(0, sh, sh + 4096);
  for (int t = 0; t < ntiles; ++t) {
    __hip_bfloat16* As = sh + (t & 1) * 8192;
    __hip_bfloat16* Bs = As + 4096;
    if (t + 1 < ntiles) {
      WAIT_LGKM0();             // other buffer's ds_reads retired before DMA
      __hip_bfloat16* An = sh + ((t + 1) & 1) * 8192;
      stage((t + 1) << 6, An, An + 4096);
      WAIT_VMCNT16();           // wait current buffer only; next stays in flight
    } else {
      WAIT_VMCNT0();
    }
    short8 af[2][4], bf[2][4];
#pragma unroll
    for (int ks = 0; ks < 2; ++ks)
#pragma unroll
      for (int i = 0; i < 4; ++i) {
        const int ar = i * 16 + frow;
        af[ks][i] = *(const short8*)(As + ar * 64 + (((ks * 4 + fk) ^ (ar & 7)) << 3));
        bf[ks][i] = *(const short8*)(Bs + ar * 64 + (((ks * 4 + fk) ^ (ar & 7)) << 3));
      }
#pragma unroll
    for (int ks = 0; ks < 2; ++ks)
#pragma unroll
      for (int i = 0; i < 4; ++i)
#pragma unroll
        for (int j = 0; j < 4; ++j)
          acc[i][j] = __builtin_amdgcn_mfma_f32_16x16x32_bf16(
              af[ks][i], bf[ks][j], acc[i][j], 0, 0, 0);
  }
}

// ---------------------------------------------------------------------------
// QKV launch: grid (64, 8, 3). z=0: Q = x@Wq^T+bq with fused quantum
// epilogue -> mix_bf (bf16); if *gateA != 1 also writes Qb fp32.
// z=1/2: conditional K/V projections (early-exit when *gateA == 1).
// ---------------------------------------------------------------------------
__global__ __launch_bounds__(64) void gemm_qkv(
    const __hip_bfloat16* __restrict__ x_bf,
    const __hip_bfloat16* __restrict__ Wq,
    const __hip_bfloat16* __restrict__ Wk,
    const __hip_bfloat16* __restrict__ Wv,
    const float* __restrict__ bq, const float* __restrict__ bk,
    const float* __restrict__ bvv,
    __hip_bfloat16* __restrict__ mix,
    float* __restrict__ Qb, float* __restrict__ Kb, float* __restrict__ Vb,
    const float* __restrict__ theta, const float* __restrict__ gateA)
{
  const int z = blockIdx.z;
  const float g = *gateA;
  if (z > 0 && g == 1.0f) return;
  const __hip_bfloat16* W = (z == 0) ? Wq : (z == 1) ? Wk : Wv;
  const float* bias = (z == 0) ? bq : (z == 1) ? bk : bvv;
  float* Cf = (z == 0) ? Qb : (z == 1) ? Kb : Vb;

  __shared__ __align__(16) __hip_bfloat16 sh[16384];
  const int lane = threadIdx.x;
  const long m0 = (long)blockIdx.x * 64;
  const long n0 = (long)blockIdx.y * 64;
  floatx4 acc[4][4];
#pragma unroll
  for (int i = 0; i < 4; ++i)
#pragma unroll
    for (int j = 0; j < 4; ++j) acc[i][j] = (floatx4){0.f, 0.f, 0.f, 0.f};

  gemm_core(x_bf, W, 512, m0, n0, lane, sh, acc);

  // D layout: row=(lane>>4)*4+reg, col=lane&15 (verified m89/m91)
  const int col_l = lane & 15;
  const int row_l = (lane >> 4) << 2;

  if (z > 0 || g != 1.0f) {
#pragma unroll
    for (int j = 0; j < 4; ++j) {
      const long col = n0 + j * 16 + col_l;
      const float bv = bias[col];
#pragma unroll
      for (int i = 0; i < 4; ++i)
#pragma unroll
        for (int r = 0; r < 4; ++r)
          Cf[(m0 + i * 16 + row_l + r) * 512 + col] = acc[i][j][r] + bv;
    }
  }
  if (z == 0) {
    // quantum epilogue: LDS-transpose acc(+bias), then per 8-wide head
    // group o[0]=c1..c7, o[j>=1]=c0..cj with c=cos(q+theta). Single wave:
    // DS pipe in-order; lgkm fences pin ordering/completion.
    float* shf = (float*)sh;   // 64x64 fp32 = 16 KB
    WAIT_LGKM0();
#pragma unroll
    for (int j = 0; j < 4; ++j) {
      const long col = n0 + j * 16 + col_l;
      const float bv = bias[col];
#pragma unroll
      for (int i = 0; i < 4; ++i)
#pragma unroll
        for (int r = 0; r < 4; ++r)
          shf[(i * 16 + row_l + r) * 64 + j * 16 + col_l] = acc[i][j][r] + bv;
    }
    WAIT_LGKM0();
    float th[8];
#pragma unroll
    for (int i = 0; i < 8; ++i) th[i] = theta[i];
#pragma unroll
    for (int t = 0; t < 8; ++t) {
      const int gidx = t * 64 + lane;
      const int row = gidx >> 3;
      const int hh = gidx & 7;
      const float* src = shf + row * 64 + hh * 8;
      float c[8];
#pragma unroll
      for (int i = 0; i < 8; ++i) c[i] = __cosf(src[i] + th[i]);
      float o[8];
      float p = c[1];
#pragma unroll
      for (int i = 2; i < 8; ++i) p *= c[i];
      o[0] = p;
      float cp = c[0];
#pragma unroll
      for (int i = 1; i < 8; ++i) { cp *= c[i]; o[i] = cp; }
      union { unsigned short u16[8]; uint4 v; } pk;
#pragma unroll
      for (int i = 0; i < 8; ++i) pk.u16[i] = f2bf_bits(o[i]);
      *(uint4*)(mix + (m0 + row) * 512 + n0 + hh * 8) = pk.v;
    }
  }
}

// ---------------------------------------------------------------------------
// Plain GEMM: C = A @ W^T + bias (fp32 out). grid (M/64, N/64).
// ---------------------------------------------------------------------------
__global__ __launch_bounds__(64) void gemm_plain(
    const __hip_bfloat16* __restrict__ A,
    const __hip_bfloat16* __restrict__ W,
    const float* __restrict__ bias, float* __restrict__ C, int N, int K)
{
  __shared__ __align__(16) __hip_bfloat16 sh[16384];
  const int lane = threadIdx.x;
  const long m0 = (long)blockIdx.x * 64;
  const long n0 = (long)blockIdx.y * 64;
  floatx4 acc[4][4];
#pragma unroll
  for (int i = 0; i < 4; ++i)
#pragma unroll
    for (int j = 0; j < 4; ++j) acc[i][j] = (floatx4){0.f, 0.f, 0.f, 0.f};
  gemm_core(A, W, K, m0, n0, lane, sh, acc);
  const int col_l = lane & 15;
  const int row_l = (lane >> 4) << 2;
#pragma unroll
  for (int j = 0; j < 4; ++j) {
    const long col = n0 + j * 16 + col_l;
    const float bv = bias[col];
#pragma unroll
    for (int i = 0; i < 4; ++i)
#pragma unroll
      for (int r = 0; r < 4; ++r)
        C[(m0 + i * 16 + row_l + r) * N + col] = acc[i][j][r] + bv;
  }
}

// ---------------------------------------------------------------------------
// FFN-out launch: grid (64, 8, 2). z=0: Fb = hq@W2^T+b2. z=1 (cond
// gateF!=1): Fc = hc@W2^T+b2.
// ---------------------------------------------------------------------------
__global__ __launch_bounds__(64) void gemm_ffnout(
    const __hip_bfloat16* __restrict__ hq,
    const __hip_bfloat16* __restrict__ hc,
    const __hip_bfloat16* __restrict__ W2, const float* __restrict__ b2,
    float* __restrict__ Fb, float* __restrict__ Fc,
    const float* __restrict__ gateF)
{
  const int z = blockIdx.z;
  if (z == 1 && *gateF == 1.0f) return;
  const __hip_bfloat16* A = z ? hc : hq;
  float* C = z ? Fc : Fb;
  __shared__ __align__(16) __hip_bfloat16 sh[16384];
  const int lane = threadIdx.x;
  const long m0 = (long)blockIdx.x * 64;
  const long n0 = (long)blockIdx.y * 64;
  floatx4 acc[4][4];
#pragma unroll
  for (int i = 0; i < 4; ++i)
#pragma unroll
    for (int j = 0; j < 4; ++j) acc[i][j] = (floatx4){0.f, 0.f, 0.f, 0.f};
  gemm_core(A, W2, 2048, m0, n0, lane, sh, acc);
  const int col_l = lane & 15;
  const int row_l = (lane >> 4) << 2;
#pragma unroll
  for (int j = 0; j < 4; ++j) {
    const long col = n0 + j * 16 + col_l;
    const float bv = b2[col];
#pragma unroll
    for (int i = 0; i < 4; ++i)
#pragma unroll
      for (int r = 0; r < 4; ++r)
        C[(m0 + i * 16 + row_l + r) * 512 + col] = acc[i][j][r] + bv;
  }
}

// ---------------------------------------------------------------------------
// input prep: fp32->bf16 for x, Wq, Wo, W2, W1 (contiguous); conditional
// Wk/Wv when *gateA != 1. One launch.
// ---------------------------------------------------------------------------
__device__ __forceinline__ void cvt_one(const float* s, __hip_bfloat16* d, int n,
                                        long tid, long stride) {
  const int n4 = n >> 2;
  for (long i = tid; i < n4; i += stride) {
    float4 v = ((const float4*)s)[i];
    ushort4 u;
    u.x = f2bf_bits(v.x); u.y = f2bf_bits(v.y);
    u.z = f2bf_bits(v.z); u.w = f2bf_bits(v.w);
    ((ushort4*)d)[i] = u;
  }
}

__global__ __launch_bounds__(256) void prep_inputs(
    const float* x, __hip_bfloat16* x_bf,
    const float* Wq, __hip_bfloat16* Wq_bf,
    const float* Wo, __hip_bfloat16* Wo_bf,
    const float* W2, __hip_bfloat16* W2_bf,
    const float* W1, __hip_bfloat16* W1_bf,
    const float* Wk, __hip_bfloat16* Wk_bf,
    const float* Wv, __hip_bfloat16* Wv_bf,
    const float* gateA)
{
  const long stride = (long)gridDim.x * blockDim.x;
  const long tid = (long)blockIdx.x * blockDim.x + threadIdx.x;
  cvt_one(x, x_bf, 4096 * 512, tid, stride);
  cvt_one(Wq, Wq_bf, 512 * 512, tid, stride);
  cvt_one(Wo, Wo_bf, 512 * 512, tid, stride);
  cvt_one(W2, W2_bf, 512 * 2048, tid, stride);
  cvt_one(W1, W1_bf, 2048 * 8, tid, stride);
  if (*gateA != 1.0f) {
    cvt_one(Wk, Wk_bf, 512 * 512, tid, stride);
    cvt_one(Wv, Wv_bf, 512 * 512, tid, stride);
  }
}

// ---------------------------------------------------------------------------
// [cond gateA!=1] classical softmax attention + blend into mix (bf16).
// One thread per (b,h,s), online softmax over 1024 keys, DK=8.
// ---------------------------------------------------------------------------
__global__ __launch_bounds__(256) void attn_blend(
    const float* __restrict__ Qb, const float* __restrict__ Kb,
    const float* __restrict__ Vb, __hip_bfloat16* __restrict__ mix,
    const float* __restrict__ gateA)
{
  const float g = *gateA;
  if (g == 1.0f) return;
  const int idx = blockIdx.x * blockDim.x + threadIdx.x;
  if (idx >= 4 * 64 * 1024) return;
  const int s = idx & 1023;
  const int h = (idx >> 10) & 63;
  const int b = idx >> 16;
  const long qoff = ((long)(b * 1024 + s)) * 512 + h * 8;
  float q[8];
#pragma unroll
  for (int i = 0; i < 8; ++i) q[i] = Qb[qoff + i] * 0.35355339059327373f;
  float m = -INFINITY, l = 0.0f, acc[8];
#pragma unroll
  for (int i = 0; i < 8; ++i) acc[i] = 0.0f;
  for (int t = 0; t < 1024; ++t) {
    const long koff = ((long)(b * 1024 + t)) * 512 + h * 8;
    const float* kr = Kb + koff;
    const float* vr = Vb + koff;
    float sc = 0.0f;
#pragma unroll
    for (int i = 0; i < 8; ++i) sc += q[i] * kr[i];
    float nm = fmaxf(m, sc);
    float corr = __expf(m - nm);
    float p = __expf(sc - nm);
    l = l * corr + p;
#pragma unroll
    for (int i = 0; i < 8; ++i) acc[i] = acc[i] * corr + p * vr[i];
    m = nm;
  }
  const float inv = 1.0f / l;
  union { unsigned short u16[8]; uint4 v; } pk;
  pk.v = *(const uint4*)(mix + qoff);
#pragma unroll
  for (int i = 0; i < 8; ++i) {
    float quant = bfbits2f(pk.u16[i]);
    pk.u16[i] = f2bf_bits(g * quant + (1.0f - g) * acc[i] * inv);
  }
  *(uint4*)(mix + qoff) = pk.v;
}

// ---------------------------------------------------------------------------
// LN1 + FFN-h fused. Block = 256 threads = 4 rows (wave-per-row LN, shfl
// only). Then all threads hold W1 (2048x8 bf16) slices in registers and
// compute hq = relu(qm @ W1^T + b1) -> bf16 (and hc from xs when gateF!=1).
// Removes the ffn_h GEMM launch + qm/xs round-trips. grid 1024.
// ---------------------------------------------------------------------------
__global__ __launch_bounds__(256) void lnffn2(
    const float* __restrict__ x, const float* __restrict__ attn,
    const float* __restrict__ lw, const float* __restrict__ lb,
    float* __restrict__ x1, const float* __restrict__ phi,
    const __hip_bfloat16* __restrict__ W1_bf, const float* __restrict__ b1,
    __hip_bfloat16* __restrict__ hq, __hip_bfloat16* __restrict__ hc,
    const float* __restrict__ gateF)
{
  const int tid = threadIdx.x;
  const int wv = tid >> 6, lane = tid & 63;
  const int row = blockIdx.x * 4 + wv;
  const long base = (long)row * 512;
  const int c0 = lane * 8;
  __shared__ float qrow[4][8];
  __shared__ float xsrow[4][8];

  float4 a0 = *(const float4*)(x + base + c0);
  float4 a1 = *(const float4*)(x + base + c0 + 4);
  float4 b0 = *(const float4*)(attn + base + c0);
  float4 b1v4 = *(const float4*)(attn + base + c0 + 4);
  float s[8] = {a0.x + b0.x, a0.y + b0.y, a0.z + b0.z, a0.w + b0.w,
                a1.x + b1v4.x, a1.y + b1v4.y, a1.z + b1v4.z, a1.w + b1v4.w};
  float sum = 0.f, ssq = 0.f;
#pragma unroll
  for (int i = 0; i < 8; ++i) { sum += s[i]; ssq += s[i] * s[i]; }
#pragma unroll
  for (int off = 32; off > 0; off >>= 1) {
    sum += __shfl_xor(sum, off);
    ssq += __shfl_xor(ssq, off);
  }
  const float mean = sum * (1.0f / 512.0f);
  const float var = ssq * (1.0f / 512.0f) - mean * mean;
  const float rstd = rsqrtf(fmaxf(var, 0.0f) + 1e-5f);
  float4 w0 = *(const float4*)(lw + c0);
  float4 w1 = *(const float4*)(lw + c0 + 4);
  float4 g0 = *(const float4*)(lb + c0);
  float4 g1 = *(const float4*)(lb + c0 + 4);
  float o[8];
  const float wf[8] = {w0.x, w0.y, w0.z, w0.w, w1.x, w1.y, w1.z, w1.w};
  const float gf8[8] = {g0.x, g0.y, g0.z, g0.w, g1.x, g1.y, g1.z, g1.w};
#pragma unroll
  for (int i = 0; i < 8; ++i) o[i] = (s[i] - mean) * rstd * wf[i] + gf8[i];
  *(float4*)(x1 + base + c0) = (float4){o[0], o[1], o[2], o[3]};
  *(float4*)(x1 + base + c0 + 4) = (float4){o[4], o[5], o[6], o[7]};
  if (lane == 0) {
#pragma unroll
    for (int i = 0; i < 8; ++i) {
      qrow[wv][i] = __cosf(o[i]) * __cosf(phi[i]);
      xsrow[wv][i] = o[i];
    }
  }
  __syncthreads();

  // FFN-h: thread owns outputs n = tid*8 .. tid*8+7 for all 4 rows.
  float w1f[8][8];
#pragma unroll
  for (int j = 0; j < 8; ++j) {
    uint4 wr = *(const uint4*)(W1_bf + (long)(tid * 8 + j) * 8);
    const unsigned short* pu = (const unsigned short*)&wr;
#pragma unroll
    for (int k = 0; k < 8; ++k) w1f[j][k] = bfbits2f(pu[k]);
  }
  float4 bb0 = *(const float4*)(b1 + tid * 8);
  float4 bb1 = *(const float4*)(b1 + tid * 8 + 4);
  const float b1v[8] = {bb0.x, bb0.y, bb0.z, bb0.w, bb1.x, bb1.y, bb1.z, bb1.w};
  const float gv = *gateF;
#pragma unroll
  for (int r = 0; r < 4; ++r) {
    const long rowr = (long)blockIdx.x * 4 + r;
    float qm[8];
#pragma unroll
    for (int k = 0; k < 8; ++k) qm[k] = qrow[r][k];
    union { unsigned short u16[8]; uint4 v; } pk;
#pragma unroll
    for (int j = 0; j < 8; ++j) {
      float acc = b1v[j];
#pragma unroll
      for (int k = 0; k < 8; ++k) acc += qm[k] * w1f[j][k];
      pk.u16[j] = f2bf_bits(fmaxf(acc, 0.0f));
    }
    *(uint4*)(hq + rowr * 2048 + tid * 8) = pk.v;
    if (gv != 1.0f) {
      float xs[8];
#pragma unroll
      for (int k = 0; k < 8; ++k) xs[k] = xsrow[r][k];
#pragma unroll
      for (int j = 0; j < 8; ++j) {
        float acc = b1v[j];
#pragma unroll
        for (int k = 0; k < 8; ++k) acc += xs[k] * w1f[j][k];
        pk.u16[j] = f2bf_bits(fmaxf(acc, 0.0f));
      }
      *(uint4*)(hc + rowr * 2048 + tid * 8) = pk.v;
    }
  }
}

// ---------------------------------------------------------------------------
// Final LN: out = LN(x1 + mix(Fb, Fc; gateF)). Wave-per-row, 4 rows/block,
// no barriers. grid 1024.
// ---------------------------------------------------------------------------
__global__ __launch_bounds__(256) void add_ln3(
    const float* __restrict__ x1, const float* __restrict__ Fb,
    const float* __restrict__ Fc, const float* __restrict__ gateF,
    const float* __restrict__ lw, const float* __restrict__ lb,
    float* __restrict__ out)
{
  const int tid = threadIdx.x;
  const int wv = tid >> 6, lane = tid & 63;
  const int row = blockIdx.x * 4 + wv;
  const long base = (long)row * 512;
  const int c0 = lane * 8;
  float4 a0 = *(const float4*)(x1 + base + c0);
  float4 a1 = *(const float4*)(x1 + base + c0 + 4);
  float4 f0 = *(const float4*)(Fb + base + c0);
  float4 f1 = *(const float4*)(Fb + base + c0 + 4);
  float s[8];
  const float gv = *gateF;
  if (gv != 1.0f) {
    float4 c0v = *(const float4*)(Fc + base + c0);
    float4 c1v = *(const float4*)(Fc + base + c0 + 4);
    const float om = 1.0f - gv;
    s[0] = a0.x + gv * f0.x + om * c0v.x; s[1] = a0.y + gv * f0.y + om * c0v.y;
    s[2] = a0.z + gv * f0.z + om * c0v.z; s[3] = a0.w + gv * f0.w + om * c0v.w;
    s[4] = a1.x + gv * f1.x + om * c1v.x; s[5] = a1.y + gv * f1.y + om * c1v.y;
    s[6] = a1.z + gv * f1.z + om * c1v.z; s[7] = a1.w + gv * f1.w + om * c1v.w;
  } else {
    s[0] = a0.x + f0.x; s[1] = a0.y + f0.y; s[2] = a0.z + f0.z; s[3] = a0.w + f0.w;
    s[4] = a1.x + f1.x; s[5] = a1.y + f1.y; s[6] = a1.z + f1.z; s[7] = a1.w + f1.w;
  }
  float sum = 0.f, ssq = 0.f;
#pragma unroll
  for (int i = 0; i < 8; ++i) { sum += s[i]; ssq += s[i] * s[i]; }
#pragma unroll
  for (int off = 32; off > 0; off >>= 1) {
    sum += __shfl_xor(sum, off);
    ssq += __shfl_xor(ssq, off);
  }
  const float mean = sum * (1.0f / 512.0f);
  const float var = ssq * (1.0f / 512.0f) - mean * mean;
  const float rstd = rsqrtf(fmaxf(var, 0.0f) + 1e-5f);
  float4 w0 = *(const float4*)(lw + c0);
  float4 w1 = *(const float4*)(lw + c0 + 4);
  float4 g0 = *(const float4*)(lb + c0);
  float4 g1 = *(const float4*)(lb + c0 + 4);
  const float wf[8] = {w0.x, w0.y, w0.z, w0.w, w1.x, w1.y, w1.z, w1.w};
  const float gf8[8] = {g0.x, g0.y, g0.z, g0.w, g1.x, g1.y, g1.z, g1.w};
  float o[8];
#pragma unroll
  for (int i = 0; i < 8; ++i) o[i] = (s[i] - mean) * rstd * wf[i] + gf8[i];
  *(float4*)(out + base + c0) = (float4){o[0], o[1], o[2], o[3]};
  *(float4*)(out + base + c0 + 4) = (float4){o[4], o[5], o[6], o[7]};
}

// ---------------------------------------------------------------------------
extern "C" void kernel_launch(void* const* d_in, const int* in_sizes, int n_in,
                              void* d_out, int out_size, void* d_ws, size_t ws_size,
                              hipStream_t stream) {
  const float* x     = (const float*)d_in[0];
  const float* Wq    = (const float*)d_in[1];
  const float* bq    = (const float*)d_in[2];
  const float* Wk    = (const float*)d_in[3];
  const float* bk    = (const float*)d_in[4];
  const float* Wv    = (const float*)d_in[5];
  const float* bv    = (const float*)d_in[6];
  const float* theta = (const float*)d_in[7];
  const float* gateA = (const float*)d_in[8];
  const float* Wo    = (const float*)d_in[9];
  const float* bo    = (const float*)d_in[10];
  const float* ln1w  = (const float*)d_in[11];
  const float* ln1b  = (const float*)d_in[12];
  const float* W1    = (const float*)d_in[13];
  const float* b1    = (const float*)d_in[14];
  const float* W2    = (const float*)d_in[15];
  const float* b2    = (const float*)d_in[16];
  const float* phi   = (const float*)d_in[17];
  const float* gateF = (const float*)d_in[18];
  const float* ln2w  = (const float*)d_in[19];
  const float* ln2b  = (const float*)d_in[20];
  float* out = (float*)d_out;

  const size_t MB = 1024 * 1024;
  char* wsb = (char*)d_ws;
  __hip_bfloat16* x_bf   = (__hip_bfloat16*)(wsb + 0 * MB);             // 4 MB
  __hip_bfloat16* Wq_bf  = (__hip_bfloat16*)(wsb + 4 * MB);             // 0.5 MB
  __hip_bfloat16* Wo_bf  = (__hip_bfloat16*)(wsb + 4 * MB + 512 * 1024);
  __hip_bfloat16* W2_bf  = (__hip_bfloat16*)(wsb + 5 * MB);             // 2 MB
  __hip_bfloat16* W1_bf  = (__hip_bfloat16*)(wsb + 7 * MB);             // 32 KB
  __hip_bfloat16* mix_bf = (__hip_bfloat16*)(wsb + 8 * MB);             // 4 MB
  float*          attn   = (float*)(wsb + 12 * MB);                     // 8 MB
  float*          x1     = (float*)(wsb + 20 * MB);                     // 8 MB
  __hip_bfloat16* hq_bf  = (__hip_bfloat16*)(wsb + 28 * MB);            // 16 MB
  float*          Fb     = (float*)(wsb + 44 * MB);                     // 8 MB
  // conditional (gate != 1) buffers
  float*          Qb     = (float*)(wsb + 52 * MB);                     // 8 MB
  __hip_bfloat16* Wk_bf  = (__hip_bfloat16*)(wsb + 60 * MB);
  __hip_bfloat16* Wv_bf  = (__hip_bfloat16*)(wsb + 60 * MB + 512 * 1024);
  float*          Kb2    = (float*)(wsb + 61 * MB);                     // 8 MB
  float*          Vb2    = (float*)(wsb + 69 * MB);                     // 8 MB
  __hip_bfloat16* hc_bf  = (__hip_bfloat16*)(wsb + 77 * MB);            // 16 MB
  float*          Fc     = (float*)(wsb + 93 * MB);                     // 8 MB

  // 1. input prep (all conversions)
  prep_inputs<<<1024, 256, 0, stream>>>(
      x, x_bf, Wq, Wq_bf, Wo, Wo_bf, W2, W2_bf, W1, W1_bf,
      Wk, Wk_bf, Wv, Wv_bf, gateA);
  // 2. QKV: z=0 Q+quantum -> mix_bf (+Qb cond); z=1/2 K/V (cond)
  gemm_qkv<<<dim3(64, 8, 3), 64, 0, stream>>>(
      x_bf, Wq_bf, Wk_bf, Wv_bf, bq, bk, bv,
      mix_bf, Qb, Kb2, Vb2, theta, gateA);
  // 3. [cond] classical attention + blend into mix_bf
  attn_blend<<<1024, 256, 0, stream>>>(Qb, Kb2, Vb2, mix_bf, gateA);
  // 4. attn = mix @ Wo^T + bo
  gemm_plain<<<dim3(64, 8), 64, 0, stream>>>(
      mix_bf, Wo_bf, bo, attn, 512, 512);
  // 5. x1 = LN(x+attn); hq (= relu(qm@W1^T+b1)) fused; hc cond
  lnffn2<<<1024, 256, 0, stream>>>(
      x, attn, ln1w, ln1b, x1, phi, W1_bf, b1, hq_bf, hc_bf, gateF);
  // 6. Fb = hq @ W2^T + b2 (z=0); Fc = hc @ W2^T + b2 (z=1, cond)
  gemm_ffnout<<<dim3(64, 8, 2), 64, 0, stream>>>(
      hq_bf, hc_bf, W2_bf, b2, Fb, Fc, gateF);
  // 7. out = LN(x1 + gF*Fb + (1-gF)*Fc)
  add_ln3<<<1024, 256, 0, stream>>>(x1, Fb, Fc, gateF, ln2w, ln2b, out);
}